// Round 12
// baseline (116.915 us; speedup 1.0000x reference)
//
#include <hip/hip_runtime.h>
#include <hip/hip_bf16.h>

#define HWD 128
#define NCH 64
#define NK  9

typedef __attribute__((ext_vector_type(8))) _Float16 h16x8;
typedef __attribute__((ext_vector_type(2))) _Float16 h16x2;
typedef __attribute__((ext_vector_type(4))) float f32x4;

// async 16B global->LDS copy (dest = wave-uniform base + lane*16, linear)
__device__ __forceinline__ void async_copy16(void* lds, const void* g) {
  __builtin_amdgcn_global_load_lds(
      (const __attribute__((address_space(1))) unsigned int*)g,
      (__attribute__((address_space(3))) unsigned int*)lds, 16, 0, 0);
}

__device__ __forceinline__ int swz(int unit, int c) { return (c ^ unit) & 7; }

// ---- merged weight prep:
// w_def [64o][64c][3][3] f32 -> wbt [9k][64o][64c] fp16
// w_off [18o][64c][3][3] f32 -> wbo [9k][32o_pad][64c] fp16
__global__ void prep_weights_kernel(const float* __restrict__ wd,
                                    const float* __restrict__ wo,
                                    _Float16* __restrict__ wbt,
                                    _Float16* __restrict__ wbo) {
  int i = blockIdx.x * 256 + threadIdx.x;
  if (i < NK * 64 * 64) {
    int c = i & 63, o = (i >> 6) & 63, k = i >> 12;
    wbt[i] = (_Float16)wd[(o * 64 + c) * 9 + k];
  } else {
    int j = i - NK * 64 * 64;
    if (j < NK * 32 * 64) {
      int c = j & 63, o = (j >> 6) & 31, k = j >> 11;
      wbo[j] = (o < 18) ? (_Float16)wo[(o * 64 + c) * 9 + k] : (_Float16)0;
    }
  }
}

// ---- x NCHW f32 -> xt NHWC fp16 ----
__global__ __launch_bounds__(256) void transpose_x_kernel(const float* __restrict__ x,
                                                          _Float16* __restrict__ xt) {
  __shared__ float tile[64][129];
  int bid = blockIdx.x;
  int b = bid >> 7, h = bid & 127;
  int t = threadIdx.x;
  const float* xb = x + ((size_t)b * NCH) * HWD * HWD + (size_t)h * HWD;
  #pragma unroll 4
  for (int i = 0; i < 32; ++i) {
    int c = (t >> 7) + 2 * i;
    int w = t & 127;
    tile[c][w] = xb[(size_t)c * HWD * HWD + w];
  }
  __syncthreads();
  _Float16* xto = xt + (((size_t)b * HWD + h) * HWD) * NCH;
  #pragma unroll 4
  for (int i = 0; i < 32; ++i) {
    int idx = i * 256 + t;
    int c = idx & 63, w = idx >> 6;
    xto[(size_t)w * NCH + c] = (_Float16)tile[c][w];
  }
}

// ---- fused kernel v12: 8x16 patch, ONE barrier total.
// Weights read directly from global (L1/L2-hot broadcast; TA pipe is idle now
// that gathers are LDS-based). No weight LDS, no weight staging, no phase
// barriers: offsets exchanged in-wave via __shfl, gathers are wave-private.
// LDS = x halo only (30720 B -> 5 blocks/CU).
#define PH 8
#define PW 16
#define XR 12
#define XC 20
#define NSLOT (XR * XC)     // 240 slots, 64 halves each (128 B)

__global__ __launch_bounds__(256, 5) void fused_deform_kernel(
    const _Float16* __restrict__ xt, const _Float16* __restrict__ wbt,
    const _Float16* __restrict__ wbo, const float* __restrict__ bo,
    float* __restrict__ out)
{
  __shared__ _Float16 xlds[NSLOT * 64];    // 30720 B

  int bid = blockIdx.x;
  int cid = (bid & 7) * 128 + (bid >> 3);  // XCD swizzle (bijective, 1024 % 8 == 0)
  int wp = cid & 7;
  int hp = (cid >> 3) & 15;
  int b  = cid >> 7;
  int h0 = hp * PH, w0 = wp * PW;

  int t = threadIdx.x;
  int lane = t & 63;
  int wv = t >> 6;
  int pl = lane & 15;
  int cg = lane >> 4;
  int w = w0 + pl;

  const _Float16* xtb = xt + ((size_t)b * HWD * HWD) * NCH;

  // ---- stage x halo tile (async, source pre-swizzled, dest linear) ----
  #pragma unroll
  for (int i = 0; i < 8; ++i) {
    int idx = i * 256 + t;                 // 240 slots * 8 chunks = 1920
    if (idx < NSLOT * 8) {
      int px = idx >> 3, c8 = idx & 7;
      int r = px / XC, c = px - r * XC;
      int yr = min(max(h0 - 2 + r, 0), HWD - 1);
      int xc = min(max(w0 - 2 + c, 0), HWD - 1);
      async_copy16(xlds + idx * 8,
                   xtb + (size_t)(yr * HWD + xc) * NCH + swz(px, c8) * 8);
    }
  }
  __syncthreads();    // the ONLY barrier

  // ======== PHASE 1: offset conv (weights direct from global) ========
  f32x4 acco[2][2];   // [pg][nt]
  #pragma unroll
  for (int pg = 0; pg < 2; ++pg)
    #pragma unroll
    for (int nt = 0; nt < 2; ++nt) acco[pg][nt] = (f32x4){0.f, 0.f, 0.f, 0.f};

  #pragma unroll
  for (int k = 0; k < NK; ++k) {
    int ky = k / 3, kx = k - ky * 3;
    // A-frags from global (16x128B coalesced lines, L1-broadcast across waves)
    h16x8 a0[2], a1[2];
    #pragma unroll
    for (int nt = 0; nt < 2; ++nt) {
      const _Float16* wr = wbo + ((size_t)k * 32 + nt * 16 + pl) * 64;
      a0[nt] = *(const h16x8*)(wr + cg * 8);
      a1[nt] = *(const h16x8*)(wr + 32 + cg * 8);
    }
    #pragma unroll
    for (int pg = 0; pg < 2; ++pg) {
      int prow = wv * 2 + pg;
      int y = h0 + prow + ky - 1, x = w + kx - 1;
      bool ok = (y >= 0) & (y < HWD) & (x >= 0) & (x < HWD);
      int slot = (prow + 1 + ky) * XC + (pl + 1 + kx);
      const _Float16* sp = xlds + slot * 64;
      h16x8 b0 = *(const h16x8*)(sp + swz(slot, cg) * 8);
      h16x8 b1 = *(const h16x8*)(sp + swz(slot, cg + 4) * 8);
      if (!ok) {
        #pragma unroll
        for (int j = 0; j < 8; ++j) { b0[j] = (_Float16)0; b1[j] = (_Float16)0; }
      }
      #pragma unroll
      for (int nt = 0; nt < 2; ++nt) {
        acco[pg][nt] = __builtin_amdgcn_mfma_f32_16x16x32_f16(a0[nt], b0, acco[pg][nt], 0, 0, 0);
        acco[pg][nt] = __builtin_amdgcn_mfma_f32_16x16x32_f16(a1[nt], b1, acco[pg][nt], 0, 0, 0);
      }
    }
  }

  // ---- offset exchange IN-WAVE via shfl (D: col=pixel pl, row=oc) ----
  h16x2 oo[2][NK];    // packed (oy,ox) fp16 per pg per tap
  int base = lane & 15;
  #pragma unroll
  for (int k = 0; k < NK; ++k) {
    const int ocy = 2 * k,     nty = ocy >> 4, cgy = (ocy >> 2) & 3, ry = ocy & 3;
    const int ocx = 2 * k + 1, ntx = ocx >> 4, cgx = (ocx >> 2) & 3, rx = ocx & 3;
    float by = bo[ocy], bx = bo[ocx];
    #pragma unroll
    for (int pg = 0; pg < 2; ++pg) {
      float vy = __shfl(acco[pg][nty][ry], base + cgy * 16, 64) + by;
      float vx = __shfl(acco[pg][ntx][rx], base + cgx * 16, 64) + bx;
      oo[pg][k][0] = (_Float16)vy;
      oo[pg][k][1] = (_Float16)vx;
    }
  }

  // ======== PHASE 2: deformable conv (weights direct from global) ========
  f32x4 acc[2][4];    // [pg][nt]
  #pragma unroll
  for (int pg = 0; pg < 2; ++pg)
    #pragma unroll
    for (int nt = 0; nt < 4; ++nt) acc[pg][nt] = (f32x4){0.f, 0.f, 0.f, 0.f};

  h16x8 s0g[2], s1g[2];

  auto gather = [&](int prow, float oy, float ox, int ky, int kx,
                    h16x8& s0, h16x8& s1) {
    float py = oy + (float)(h0 + prow - 1 + ky);
    float pxf = ox + (float)(w - 1 + kx);
    float y0f = floorf(py), x0f = floorf(pxf);
    float wy1 = py - y0f, wx1 = pxf - x0f;
    float wy0 = 1.f - wy1, wx0 = 1.f - wx1;
    int y0 = (int)y0f, x0 = (int)x0f;
    int sy = y0 - (h0 - 2);
    int sx = x0 - (w0 - 2);

    #pragma unroll
    for (int j = 0; j < 8; ++j) { s0[j] = (_Float16)0; s1[j] = (_Float16)0; }

    #pragma unroll
    for (int r = 0; r < 4; ++r) {
      int dy = r >> 1, dx = r & 1;
      int yy = y0 + dy, xx = x0 + dx;
      int sr = sy + dy, sc = sx + dx;
      bool okimg = (yy >= 0) & (yy < HWD) & (xx >= 0) & (xx < HWD);
      float wtf = (dy ? wy1 : wy0) * (dx ? wx1 : wx0);
      wtf = okimg ? wtf : 0.f;
      _Float16 wzh = (_Float16)wtf;

      h16x8 g0, g1;
      bool intile = (sr >= 0) & (sr < XR) & (sc >= 0) & (sc < XC);
      if (intile) {
        int slot = sr * XC + sc;
        const _Float16* sp = xlds + slot * 64;
        g0 = *(const h16x8*)(sp + swz(slot, cg) * 8);
        g1 = *(const h16x8*)(sp + swz(slot, cg + 4) * 8);
      } else {
        // rare fallback (|offset| > ~1) or OOB-with-wt0; clamped safe read
        int yc = min(max(yy, 0), HWD - 1);
        int xc2 = min(max(xx, 0), HWD - 1);
        const _Float16* sp = xtb + (size_t)(yc * HWD + xc2) * NCH + cg * 8;
        g0 = *(const h16x8*)(sp);
        g1 = *(const h16x8*)(sp + 32);
      }
      h16x8 wzv;
      #pragma unroll
      for (int j = 0; j < 8; ++j) wzv[j] = wzh;
      s0 = g0 * wzv + s0;     // v_pk_fma_f16
      s1 = g1 * wzv + s1;
    }
  };

  #pragma unroll
  for (int k = 0; k < NK; ++k) {
    int ky = k / 3, kx = k - ky * 3;
    #pragma unroll
    for (int pg = 0; pg < 2; ++pg)
      gather(wv * 2 + pg, (float)oo[pg][k][0], (float)oo[pg][k][1],
             ky, kx, s0g[pg], s1g[pg]);
    #pragma unroll
    for (int nt = 0; nt < 4; ++nt) {
      const _Float16* wr = wbt + ((size_t)k * 64 + nt * 16 + pl) * 64;
      h16x8 a0 = *(const h16x8*)(wr + cg * 8);        // read ONCE,
      h16x8 a1 = *(const h16x8*)(wr + 32 + cg * 8);   // used for both rows
      #pragma unroll
      for (int pg = 0; pg < 2; ++pg) {
        acc[pg][nt] = __builtin_amdgcn_mfma_f32_16x16x32_f16(a0, s0g[pg], acc[pg][nt], 0, 0, 0);
        acc[pg][nt] = __builtin_amdgcn_mfma_f32_16x16x32_f16(a1, s1g[pg], acc[pg][nt], 0, 0, 0);
      }
    }
  }

  // ---- epilogue: direct coalesced stores (lanes 0-15 = 64B row segment) ----
  #pragma unroll
  for (int pg = 0; pg < 2; ++pg) {
    int hrow = h0 + wv * 2 + pg;
    #pragma unroll
    for (int nt = 0; nt < 4; ++nt) {
      #pragma unroll
      for (int r = 0; r < 4; ++r) {
        int oc = nt * 16 + cg * 4 + r;
        out[(((size_t)b * NCH + oc) * HWD + hrow) * HWD + w0 + pl] = acc[pg][nt][r];
      }
    }
  }
}

extern "C" void kernel_launch(void* const* d_in, const int* in_sizes, int n_in,
                              void* d_out, int out_size, void* d_ws, size_t ws_size,
                              hipStream_t stream) {
  const float* x     = (const float*)d_in[0];
  const float* w_off = (const float*)d_in[1];
  const float* b_off = (const float*)d_in[2];
  const float* w_def = (const float*)d_in[3];
  float* out = (float*)d_out;

  char* ws = (char*)d_ws;
  _Float16* xt  = (_Float16*)ws;                       // 8*128*128*64*2 = 16,777,216 B
  _Float16* wbt = (_Float16*)(ws + 16777216);          // 9*64*64*2      =     73,728 B
  _Float16* wbo = (_Float16*)(ws + 16777216 + 73728);  // 9*32*64*2      =     36,864 B

  hipLaunchKernelGGL(prep_weights_kernel, dim3(216),  dim3(256), 0, stream, w_def, w_off, wbt, wbo);
  hipLaunchKernelGGL(transpose_x_kernel,  dim3(1024), dim3(256), 0, stream, x, xt);
  hipLaunchKernelGGL(fused_deform_kernel, dim3(1024), dim3(256), 0, stream, xt, wbt, wbo, b_off, out);
}

// Round 13
// 85.567 us; speedup vs baseline: 1.3664x; 1.3664x over previous
//
#include <hip/hip_runtime.h>
#include <hip/hip_bf16.h>

#define HWD 128
#define NCH 64
#define NK  9

typedef __attribute__((ext_vector_type(8))) _Float16 h16x8;
typedef __attribute__((ext_vector_type(2))) _Float16 h16x2;
typedef __attribute__((ext_vector_type(4))) float f32x4;

// async 16B global->LDS copy (dest = wave-uniform base + lane*16, linear)
__device__ __forceinline__ void async_copy16(void* lds, const void* g) {
  __builtin_amdgcn_global_load_lds(
      (const __attribute__((address_space(1))) unsigned int*)g,
      (__attribute__((address_space(3))) unsigned int*)lds, 16, 0, 0);
}

__device__ __forceinline__ int swz(int unit, int c) { return (c ^ unit) & 7; }

// ---- merged weight prep:
// w_def [64o][64c][3][3] f32 -> wbt [9k][64o][64c] fp16
// w_off [18o][64c][3][3] f32 -> wbo [9k][32o_pad][64c] fp16
__global__ void prep_weights_kernel(const float* __restrict__ wd,
                                    const float* __restrict__ wo,
                                    _Float16* __restrict__ wbt,
                                    _Float16* __restrict__ wbo) {
  int i = blockIdx.x * 256 + threadIdx.x;
  if (i < NK * 64 * 64) {
    int c = i & 63, o = (i >> 6) & 63, k = i >> 12;
    wbt[i] = (_Float16)wd[(o * 64 + c) * 9 + k];
  } else {
    int j = i - NK * 64 * 64;
    if (j < NK * 32 * 64) {
      int c = j & 63, o = (j >> 6) & 31, k = j >> 11;
      wbo[j] = (o < 18) ? (_Float16)wo[(o * 64 + c) * 9 + k] : (_Float16)0;
    }
  }
}

// ---- x NCHW f32 -> xt NHWC fp16 ----
__global__ __launch_bounds__(256) void transpose_x_kernel(const float* __restrict__ x,
                                                          _Float16* __restrict__ xt) {
  __shared__ float tile[64][129];
  int bid = blockIdx.x;
  int b = bid >> 7, h = bid & 127;
  int t = threadIdx.x;
  const float* xb = x + ((size_t)b * NCH) * HWD * HWD + (size_t)h * HWD;
  #pragma unroll 4
  for (int i = 0; i < 32; ++i) {
    int c = (t >> 7) + 2 * i;
    int w = t & 127;
    tile[c][w] = xb[(size_t)c * HWD * HWD + w];
  }
  __syncthreads();
  _Float16* xto = xt + (((size_t)b * HWD + h) * HWD) * NCH;
  #pragma unroll 4
  for (int i = 0; i < 32; ++i) {
    int idx = i * 256 + t;
    int c = idx & 63, w = idx >> 6;
    xto[(size_t)w * NCH + c] = (_Float16)tile[c][w];
  }
}

// ---- fused kernel v13: v12's one-barrier structure, but with a register
// budget that FITS (launch_bounds(256,4) -> 128 VGPR; R12's (256,5) spilled
// accumulators to scratch -> 370 MB HBM traffic). Weights direct from global
// (L1/L2-hot broadcast on the otherwise-idle TA pipe); offsets via __shfl;
// LDS = x halo only (30720 B); occupancy = 4 blocks/CU VGPR-limited.
#define PH 8
#define PW 16
#define XR 12
#define XC 20
#define NSLOT (XR * XC)     // 240 slots, 64 halves each (128 B)

__global__ __launch_bounds__(256, 4) void fused_deform_kernel(
    const _Float16* __restrict__ xt, const _Float16* __restrict__ wbt,
    const _Float16* __restrict__ wbo, const float* __restrict__ bo,
    float* __restrict__ out)
{
  __shared__ _Float16 xlds[NSLOT * 64];    // 30720 B

  int bid = blockIdx.x;
  int cid = (bid & 7) * 128 + (bid >> 3);  // XCD swizzle (bijective, 1024 % 8 == 0)
  int wp = cid & 7;
  int hp = (cid >> 3) & 15;
  int b  = cid >> 7;
  int h0 = hp * PH, w0 = wp * PW;

  int t = threadIdx.x;
  int lane = t & 63;
  int wv = t >> 6;
  int pl = lane & 15;
  int cg = lane >> 4;
  int w = w0 + pl;

  const _Float16* xtb = xt + ((size_t)b * HWD * HWD) * NCH;

  // ---- stage x halo tile (async, source pre-swizzled, dest linear) ----
  #pragma unroll
  for (int i = 0; i < 8; ++i) {
    int idx = i * 256 + t;                 // 240 slots * 8 chunks = 1920
    if (idx < NSLOT * 8) {
      int px = idx >> 3, c8 = idx & 7;
      int r = px / XC, c = px - r * XC;
      int yr = min(max(h0 - 2 + r, 0), HWD - 1);
      int xc = min(max(w0 - 2 + c, 0), HWD - 1);
      async_copy16(xlds + idx * 8,
                   xtb + (size_t)(yr * HWD + xc) * NCH + swz(px, c8) * 8);
    }
  }
  __syncthreads();    // the ONLY barrier

  // ======== PHASE 1: offset conv (weights direct from global) ========
  f32x4 acco[2][2];   // [pg][nt]
  #pragma unroll
  for (int pg = 0; pg < 2; ++pg)
    #pragma unroll
    for (int nt = 0; nt < 2; ++nt) acco[pg][nt] = (f32x4){0.f, 0.f, 0.f, 0.f};

  #pragma unroll
  for (int k = 0; k < NK; ++k) {
    int ky = k / 3, kx = k - ky * 3;
    // A-frags from global (16x128B coalesced lines, L1-broadcast across waves)
    h16x8 a0[2], a1[2];
    #pragma unroll
    for (int nt = 0; nt < 2; ++nt) {
      const _Float16* wr = wbo + ((size_t)k * 32 + nt * 16 + pl) * 64;
      a0[nt] = *(const h16x8*)(wr + cg * 8);
      a1[nt] = *(const h16x8*)(wr + 32 + cg * 8);
    }
    #pragma unroll
    for (int pg = 0; pg < 2; ++pg) {
      int prow = wv * 2 + pg;
      int y = h0 + prow + ky - 1, x = w + kx - 1;
      bool ok = (y >= 0) & (y < HWD) & (x >= 0) & (x < HWD);
      int slot = (prow + 1 + ky) * XC + (pl + 1 + kx);
      const _Float16* sp = xlds + slot * 64;
      h16x8 b0 = *(const h16x8*)(sp + swz(slot, cg) * 8);
      h16x8 b1 = *(const h16x8*)(sp + swz(slot, cg + 4) * 8);
      if (!ok) {
        #pragma unroll
        for (int j = 0; j < 8; ++j) { b0[j] = (_Float16)0; b1[j] = (_Float16)0; }
      }
      #pragma unroll
      for (int nt = 0; nt < 2; ++nt) {
        acco[pg][nt] = __builtin_amdgcn_mfma_f32_16x16x32_f16(a0[nt], b0, acco[pg][nt], 0, 0, 0);
        acco[pg][nt] = __builtin_amdgcn_mfma_f32_16x16x32_f16(a1[nt], b1, acco[pg][nt], 0, 0, 0);
      }
    }
  }

  // ---- offset exchange IN-WAVE via shfl (D: col=pixel pl, row=oc) ----
  h16x2 oo[2][NK];    // packed (oy,ox) fp16 per pg per tap
  int base = lane & 15;
  #pragma unroll
  for (int k = 0; k < NK; ++k) {
    const int ocy = 2 * k,     nty = ocy >> 4, cgy = (ocy >> 2) & 3, ry = ocy & 3;
    const int ocx = 2 * k + 1, ntx = ocx >> 4, cgx = (ocx >> 2) & 3, rx = ocx & 3;
    float by = bo[ocy], bx = bo[ocx];
    #pragma unroll
    for (int pg = 0; pg < 2; ++pg) {
      float vy = __shfl(acco[pg][nty][ry], base + cgy * 16, 64) + by;
      float vx = __shfl(acco[pg][ntx][rx], base + cgx * 16, 64) + bx;
      oo[pg][k][0] = (_Float16)vy;
      oo[pg][k][1] = (_Float16)vx;
    }
  }

  // ======== PHASE 2: deformable conv (weights direct from global) ========
  f32x4 acc[2][4];    // [pg][nt]
  #pragma unroll
  for (int pg = 0; pg < 2; ++pg)
    #pragma unroll
    for (int nt = 0; nt < 4; ++nt) acc[pg][nt] = (f32x4){0.f, 0.f, 0.f, 0.f};

  h16x8 s0g[2], s1g[2];

  auto gather = [&](int prow, float oy, float ox, int ky, int kx,
                    h16x8& s0, h16x8& s1) {
    float py = oy + (float)(h0 + prow - 1 + ky);
    float pxf = ox + (float)(w - 1 + kx);
    float y0f = floorf(py), x0f = floorf(pxf);
    float wy1 = py - y0f, wx1 = pxf - x0f;
    float wy0 = 1.f - wy1, wx0 = 1.f - wx1;
    int y0 = (int)y0f, x0 = (int)x0f;
    int sy = y0 - (h0 - 2);
    int sx = x0 - (w0 - 2);

    #pragma unroll
    for (int j = 0; j < 8; ++j) { s0[j] = (_Float16)0; s1[j] = (_Float16)0; }

    #pragma unroll
    for (int r = 0; r < 4; ++r) {
      int dy = r >> 1, dx = r & 1;
      int yy = y0 + dy, xx = x0 + dx;
      int sr = sy + dy, sc = sx + dx;
      bool okimg = (yy >= 0) & (yy < HWD) & (xx >= 0) & (xx < HWD);
      float wtf = (dy ? wy1 : wy0) * (dx ? wx1 : wx0);
      wtf = okimg ? wtf : 0.f;
      _Float16 wzh = (_Float16)wtf;

      h16x8 g0, g1;
      bool intile = (sr >= 0) & (sr < XR) & (sc >= 0) & (sc < XC);
      if (intile) {
        int slot = sr * XC + sc;
        const _Float16* sp = xlds + slot * 64;
        g0 = *(const h16x8*)(sp + swz(slot, cg) * 8);
        g1 = *(const h16x8*)(sp + swz(slot, cg + 4) * 8);
      } else {
        // rare fallback (|offset| > ~1) or OOB-with-wt0; clamped safe read
        int yc = min(max(yy, 0), HWD - 1);
        int xc2 = min(max(xx, 0), HWD - 1);
        const _Float16* sp = xtb + (size_t)(yc * HWD + xc2) * NCH + cg * 8;
        g0 = *(const h16x8*)(sp);
        g1 = *(const h16x8*)(sp + 32);
      }
      h16x8 wzv;
      #pragma unroll
      for (int j = 0; j < 8; ++j) wzv[j] = wzh;
      s0 = g0 * wzv + s0;     // v_pk_fma_f16
      s1 = g1 * wzv + s1;
    }
  };

  #pragma unroll
  for (int k = 0; k < NK; ++k) {
    int ky = k / 3, kx = k - ky * 3;
    #pragma unroll
    for (int pg = 0; pg < 2; ++pg)
      gather(wv * 2 + pg, (float)oo[pg][k][0], (float)oo[pg][k][1],
             ky, kx, s0g[pg], s1g[pg]);
    #pragma unroll
    for (int nt = 0; nt < 4; ++nt) {
      const _Float16* wr = wbt + ((size_t)k * 64 + nt * 16 + pl) * 64;
      h16x8 a0 = *(const h16x8*)(wr + cg * 8);        // read ONCE,
      h16x8 a1 = *(const h16x8*)(wr + 32 + cg * 8);   // used for both rows
      #pragma unroll
      for (int pg = 0; pg < 2; ++pg) {
        acc[pg][nt] = __builtin_amdgcn_mfma_f32_16x16x32_f16(a0, s0g[pg], acc[pg][nt], 0, 0, 0);
        acc[pg][nt] = __builtin_amdgcn_mfma_f32_16x16x32_f16(a1, s1g[pg], acc[pg][nt], 0, 0, 0);
      }
    }
  }

  // ---- epilogue: direct coalesced stores (lanes 0-15 = 64B row segment) ----
  #pragma unroll
  for (int pg = 0; pg < 2; ++pg) {
    int hrow = h0 + wv * 2 + pg;
    #pragma unroll
    for (int nt = 0; nt < 4; ++nt) {
      #pragma unroll
      for (int r = 0; r < 4; ++r) {
        int oc = nt * 16 + cg * 4 + r;
        out[(((size_t)b * NCH + oc) * HWD + hrow) * HWD + w0 + pl] = acc[pg][nt][r];
      }
    }
  }
}

extern "C" void kernel_launch(void* const* d_in, const int* in_sizes, int n_in,
                              void* d_out, int out_size, void* d_ws, size_t ws_size,
                              hipStream_t stream) {
  const float* x     = (const float*)d_in[0];
  const float* w_off = (const float*)d_in[1];
  const float* b_off = (const float*)d_in[2];
  const float* w_def = (const float*)d_in[3];
  float* out = (float*)d_out;

  char* ws = (char*)d_ws;
  _Float16* xt  = (_Float16*)ws;                       // 8*128*128*64*2 = 16,777,216 B
  _Float16* wbt = (_Float16*)(ws + 16777216);          // 9*64*64*2      =     73,728 B
  _Float16* wbo = (_Float16*)(ws + 16777216 + 73728);  // 9*32*64*2      =     36,864 B

  hipLaunchKernelGGL(prep_weights_kernel, dim3(216),  dim3(256), 0, stream, w_def, w_off, wbt, wbo);
  hipLaunchKernelGGL(transpose_x_kernel,  dim3(1024), dim3(256), 0, stream, x, xt);
  hipLaunchKernelGGL(fused_deform_kernel, dim3(1024), dim3(256), 0, stream, xt, wbt, wbo, b_off, out);
}

// Round 14
// 56.315 us; speedup vs baseline: 2.0761x; 1.5194x over previous
//
#include <hip/hip_runtime.h>
#include <hip/hip_bf16.h>

#define HWD 128
#define NCH 64
#define NK  9

typedef __attribute__((ext_vector_type(8))) _Float16 h16x8;
typedef __attribute__((ext_vector_type(2))) _Float16 h16x2;
typedef __attribute__((ext_vector_type(4))) float f32x4;

// async 16B global->LDS copy (dest = wave-uniform base + lane*16, linear)
__device__ __forceinline__ void async_copy16(void* lds, const void* g) {
  __builtin_amdgcn_global_load_lds(
      (const __attribute__((address_space(1))) unsigned int*)g,
      (__attribute__((address_space(3))) unsigned int*)lds, 16, 0, 0);
}

__device__ __forceinline__ int swz(int unit, int c) { return (c ^ unit) & 7; }

// ---- merged weight prep:
// w_def [64o][64c][3][3] f32 -> wbt [9k][64o][64c] fp16
// w_off [18o][64c][3][3] f32 -> wbo [9k][32o_pad][64c] fp16
__global__ void prep_weights_kernel(const float* __restrict__ wd,
                                    const float* __restrict__ wo,
                                    _Float16* __restrict__ wbt,
                                    _Float16* __restrict__ wbo) {
  int i = blockIdx.x * 256 + threadIdx.x;
  if (i < NK * 64 * 64) {
    int c = i & 63, o = (i >> 6) & 63, k = i >> 12;
    wbt[i] = (_Float16)wd[(o * 64 + c) * 9 + k];
  } else {
    int j = i - NK * 64 * 64;
    if (j < NK * 32 * 64) {
      int c = j & 63, o = (j >> 6) & 31, k = j >> 11;
      wbo[j] = (o < 18) ? (_Float16)wo[(o * 64 + c) * 9 + k] : (_Float16)0;
    }
  }
}

// ---- x NCHW f32 -> xt NHWC fp16 ----
__global__ __launch_bounds__(256) void transpose_x_kernel(const float* __restrict__ x,
                                                          _Float16* __restrict__ xt) {
  __shared__ float tile[64][129];
  int bid = blockIdx.x;
  int b = bid >> 7, h = bid & 127;
  int t = threadIdx.x;
  const float* xb = x + ((size_t)b * NCH) * HWD * HWD + (size_t)h * HWD;
  #pragma unroll 4
  for (int i = 0; i < 32; ++i) {
    int c = (t >> 7) + 2 * i;
    int w = t & 127;
    tile[c][w] = xb[(size_t)c * HWD * HWD + w];
  }
  __syncthreads();
  _Float16* xto = xt + (((size_t)b * HWD + h) * HWD) * NCH;
  #pragma unroll 4
  for (int i = 0; i < 32; ++i) {
    int idx = i * 256 + t;
    int c = idx & 63, w = idx >> 6;
    xto[(size_t)w * NCH + c] = (_Float16)tile[c][w];
  }
}

// ---- fused kernel v14: R8 structure (best measured: 42.1 us) + in-wave shfl
// offset exchange (validated in R11-R13). 4x16 patch; x halo + double-buffered
// weight taps in LDS; one barrier per tap; LDS epilogue. 36864 B -> 4 blk/CU.
#define PH 4
#define PW 16
#define XR 8
#define XC 20
#define NSLOT (XR * XC)     // 160 slots, 64 halves each (128 B)

__global__ __launch_bounds__(256, 4) void fused_deform_kernel(
    const _Float16* __restrict__ xt, const _Float16* __restrict__ wbt,
    const _Float16* __restrict__ wbo, const float* __restrict__ bo,
    float* __restrict__ out)
{
  __shared__ _Float16 xlds[NSLOT * 64];    // 20480 B (reused as f32 epilogue buf)
  __shared__ _Float16 wlds[2 * 64 * 64];   // 16384 B: two 8 KB weight buffers

  int bid = blockIdx.x;
  int cid = (bid & 7) * 256 + (bid >> 3);  // XCD swizzle (bijective, 2048 % 8 == 0)
  int wp = cid & 7;
  int hp = (cid >> 3) & 31;
  int b  = cid >> 8;
  int h0 = hp * PH, w0 = wp * PW;

  int t = threadIdx.x;
  int lane = t & 63;
  int wv = t >> 6;
  int pl = lane & 15;
  int cg = lane >> 4;
  int p  = wv * 16 + pl;          // pixel index in 4x16 patch
  int hh = p >> 4, ww = p & 15;
  int h = h0 + hh, w = w0 + ww;

  const _Float16* xtb = xt + ((size_t)b * HWD * HWD) * NCH;

  // ---- stage x halo tile (async, source pre-swizzled, dest linear) ----
  #pragma unroll
  for (int i = 0; i < 5; ++i) {
    int idx = i * 256 + t;                 // 160 slots * 8 chunks = 1280
    int px = idx >> 3, c8 = idx & 7;
    int r = px / XC, c = px - r * XC;
    int yr = min(max(h0 - 2 + r, 0), HWD - 1);
    int xc = min(max(w0 - 2 + c, 0), HWD - 1);
    async_copy16(xlds + idx * 8,
                 xtb + (size_t)(yr * HWD + xc) * NCH + swz(px, c8) * 8);
  }

  // ---- weight stagers: one tap into buffer buf (async, swizzled source) ----
  auto stage_wbo_tap = [&](int k, int buf) {       // 32 rows x 8 chunks = 256
    int row = t >> 3, c8 = t & 7;
    async_copy16(wlds + buf * 4096 + t * 8,
                 wbo + ((size_t)k * 32 + row) * 64 + swz(row, c8) * 8);
  };
  auto stage_wbt_tap = [&](int k, int buf) {       // 64 rows x 8 chunks = 512
    #pragma unroll
    for (int i = 0; i < 2; ++i) {
      int idx = i * 256 + t;
      int row = idx >> 3, c8 = idx & 7;
      async_copy16(wlds + buf * 4096 + idx * 8,
                   wbt + ((size_t)k * 64 + row) * 64 + swz(row, c8) * 8);
    }
  };

  stage_wbo_tap(0, 0);
  __syncthreads();    // all staging (x halo + wbo tap0) complete

  // ======== PHASE 1: offset conv ========
  f32x4 acc2[2];
  acc2[0] = (f32x4){0.f, 0.f, 0.f, 0.f};
  acc2[1] = (f32x4){0.f, 0.f, 0.f, 0.f};

  auto tap1 = [&](int k, int buf) {
    int ky = k / 3, kx = k - ky * 3;
    int y = h + ky - 1, x = w + kx - 1;
    bool ok = (y >= 0) & (y < HWD) & (x >= 0) & (x < HWD);
    int slot = (hh + ky + 1) * XC + (ww + kx + 1);
    const _Float16* sp = xlds + slot * 64;
    h16x8 b0 = *(const h16x8*)(sp + swz(slot, cg) * 8);
    h16x8 b1 = *(const h16x8*)(sp + swz(slot, cg + 4) * 8);
    if (!ok) {
      #pragma unroll
      for (int j = 0; j < 8; ++j) { b0[j] = (_Float16)0; b1[j] = (_Float16)0; }
    }
    const _Float16* wb = wlds + buf * 4096;
    #pragma unroll
    for (int nt = 0; nt < 2; ++nt) {
      int row = nt * 16 + pl;
      h16x8 a0 = *(const h16x8*)(wb + row * 64 + swz(row, cg) * 8);
      h16x8 a1 = *(const h16x8*)(wb + row * 64 + swz(row, cg + 4) * 8);
      acc2[nt] = __builtin_amdgcn_mfma_f32_16x16x32_f16(a0, b0, acc2[nt], 0, 0, 0);
      acc2[nt] = __builtin_amdgcn_mfma_f32_16x16x32_f16(a1, b1, acc2[nt], 0, 0, 0);
    }
  };

  #pragma unroll
  for (int k = 0; k < NK; ++k) {
    if (k < NK - 1) stage_wbo_tap(k + 1, (k + 1) & 1);
    tap1(k, k & 1);
    __syncthreads();
  }

  // prefetch wbt tap0 into buf0 (last read of buf0 was tap1(8), barrier passed)
  stage_wbt_tap(0, 0);

  // ---- offset exchange IN-WAVE via shfl (no LDS buffer, no extra barrier).
  // D layout: col=pixel (lane&15), row=oc ((lane>>4)*4+r+16nt). Thread needs
  // offsets for its own pixel p (same pl) -> source lane = pl + cgy*16.
  h16x2 oo[NK];
  int base = lane & 15;
  #pragma unroll
  for (int k = 0; k < NK; ++k) {
    const int ocy = 2 * k,     nty = ocy >> 4, cgy = (ocy >> 2) & 3, ry = ocy & 3;
    const int ocx = 2 * k + 1, ntx = ocx >> 4, cgx = (ocx >> 2) & 3, rx = ocx & 3;
    float vy = __shfl(acc2[nty][ry], base + cgy * 16, 64) + bo[ocy];
    float vx = __shfl(acc2[ntx][rx], base + cgx * 16, 64) + bo[ocx];
    oo[k][0] = (_Float16)vy;
    oo[k][1] = (_Float16)vx;
  }
  __syncthreads();    // wbt tap0 staged (vmcnt drained)

  // ======== PHASE 2: deformable conv ========
  f32x4 acc[4];
  #pragma unroll
  for (int nt = 0; nt < 4; ++nt) acc[nt] = (f32x4){0.f, 0.f, 0.f, 0.f};

  auto tap2 = [&](int k, int buf) {
    int ky = k / 3, kx = k - ky * 3;
    float py = (float)oo[k][0] + (float)(h - 1 + ky);
    float pxf = (float)oo[k][1] + (float)(w - 1 + kx);
    float y0f = floorf(py), x0f = floorf(pxf);
    float wy1 = py - y0f, wx1 = pxf - x0f;
    float wy0 = 1.f - wy1, wx0 = 1.f - wx1;
    int y0 = (int)y0f, x0 = (int)x0f;
    int sy = y0 - (h0 - 2);
    int sx = x0 - (w0 - 2);

    h16x8 s0, s1;
    #pragma unroll
    for (int j = 0; j < 8; ++j) { s0[j] = (_Float16)0; s1[j] = (_Float16)0; }

    #pragma unroll
    for (int r = 0; r < 4; ++r) {
      int dy = r >> 1, dx = r & 1;
      int yy = y0 + dy, xx = x0 + dx;
      int sr = sy + dy, sc = sx + dx;
      bool okimg = (yy >= 0) & (yy < HWD) & (xx >= 0) & (xx < HWD);
      float wtf = (dy ? wy1 : wy0) * (dx ? wx1 : wx0);
      wtf = okimg ? wtf : 0.f;
      _Float16 wzh = (_Float16)wtf;

      h16x8 g0, g1;
      bool intile = (sr >= 0) & (sr < XR) & (sc >= 0) & (sc < XC);
      if (intile) {
        int slot = sr * XC + sc;
        const _Float16* sp = xlds + slot * 64;
        g0 = *(const h16x8*)(sp + swz(slot, cg) * 8);
        g1 = *(const h16x8*)(sp + swz(slot, cg + 4) * 8);
      } else {
        // rare fallback (|offset| > ~1) or OOB-with-wt0; clamped safe read
        int yc = min(max(yy, 0), HWD - 1);
        int xc2 = min(max(xx, 0), HWD - 1);
        const _Float16* sp = xtb + (size_t)(yc * HWD + xc2) * NCH + cg * 8;
        g0 = *(const h16x8*)(sp);
        g1 = *(const h16x8*)(sp + 32);
      }
      h16x8 wzv;
      #pragma unroll
      for (int j = 0; j < 8; ++j) wzv[j] = wzh;
      s0 = g0 * wzv + s0;     // v_pk_fma_f16
      s1 = g1 * wzv + s1;
    }

    const _Float16* wb = wlds + buf * 4096;
    #pragma unroll
    for (int nt = 0; nt < 4; ++nt) {
      int row = nt * 16 + pl;
      h16x8 a0 = *(const h16x8*)(wb + row * 64 + swz(row, cg) * 8);
      h16x8 a1 = *(const h16x8*)(wb + row * 64 + swz(row, cg + 4) * 8);
      acc[nt] = __builtin_amdgcn_mfma_f32_16x16x32_f16(a0, s0, acc[nt], 0, 0, 0);
      acc[nt] = __builtin_amdgcn_mfma_f32_16x16x32_f16(a1, s1, acc[nt], 0, 0, 0);
    }
  };

  #pragma unroll
  for (int k = 0; k < NK; ++k) {
    if (k < NK - 1) stage_wbt_tap(k + 1, (k + 1) & 1);
    tap2(k, k & 1);
    __syncthreads();
  }

  // ---- epilogue: D col=pixel p, row=oc. Stage via LDS (reuse xlds). ----
  float* ost = (float*)xlds;   // [64 oc][65] = 16640 B
  #pragma unroll
  for (int nt = 0; nt < 4; ++nt) {
    int oc = nt * 16 + cg * 4;
    #pragma unroll
    for (int r = 0; r < 4; ++r)
      ost[(oc + r) * 65 + p] = acc[nt][r];
  }
  __syncthreads();
  #pragma unroll
  for (int i = 0; i < 16; ++i) {
    int idx = i * 256 + t;
    int pp = idx & 63, oc = idx >> 6;
    int hh2 = pp >> 4, ww2 = pp & 15;
    out[(((size_t)b * NCH + oc) * HWD + h0 + hh2) * HWD + w0 + ww2] = ost[oc * 65 + pp];
  }
}

extern "C" void kernel_launch(void* const* d_in, const int* in_sizes, int n_in,
                              void* d_out, int out_size, void* d_ws, size_t ws_size,
                              hipStream_t stream) {
  const float* x     = (const float*)d_in[0];
  const float* w_off = (const float*)d_in[1];
  const float* b_off = (const float*)d_in[2];
  const float* w_def = (const float*)d_in[3];
  float* out = (float*)d_out;

  char* ws = (char*)d_ws;
  _Float16* xt  = (_Float16*)ws;                       // 8*128*128*64*2 = 16,777,216 B
  _Float16* wbt = (_Float16*)(ws + 16777216);          // 9*64*64*2      =     73,728 B
  _Float16* wbo = (_Float16*)(ws + 16777216 + 73728);  // 9*32*64*2      =     36,864 B

  hipLaunchKernelGGL(prep_weights_kernel, dim3(216),  dim3(256), 0, stream, w_def, w_off, wbt, wbo);
  hipLaunchKernelGGL(transpose_x_kernel,  dim3(1024), dim3(256), 0, stream, x, xt);
  hipLaunchKernelGGL(fused_deform_kernel, dim3(2048), dim3(256), 0, stream, xt, wbt, wbo, b_off, out);
}

// Round 15
// 51.751 us; speedup vs baseline: 2.2592x; 1.0882x over previous
//
#include <hip/hip_runtime.h>
#include <hip/hip_bf16.h>

#define HWD 128
#define NCH 64
#define NK  9

typedef __attribute__((ext_vector_type(8))) _Float16 h16x8;
typedef __attribute__((ext_vector_type(2))) _Float16 h16x2;
typedef __attribute__((ext_vector_type(4))) float f32x4;

// async 16B global->LDS copy (dest = wave-uniform base + lane*16, linear)
__device__ __forceinline__ void async_copy16(void* lds, const void* g) {
  __builtin_amdgcn_global_load_lds(
      (const __attribute__((address_space(1))) unsigned int*)g,
      (__attribute__((address_space(3))) unsigned int*)lds, 16, 0, 0);
}

__device__ __forceinline__ int swz(int unit, int c) { return (c ^ unit) & 7; }

// ---- merged prep + transpose kernel.
// Blocks 0..1023: x NCHW f32 -> xt NHWC fp16, XCD-ALIGNED (b = bid&7 so image b
//   is written by XCD b — the same XCD that reads it in the fused kernel).
// Blocks 1024..1239: weight prep (wbt [9k][64o][64c], wbo [9k][32o][64c] fp16).
__global__ __launch_bounds__(256) void prep_transpose_kernel(
    const float* __restrict__ x, const float* __restrict__ wd,
    const float* __restrict__ wo, _Float16* __restrict__ xt,
    _Float16* __restrict__ wbt, _Float16* __restrict__ wbo) {
  __shared__ float tile[64][129];
  int bid = blockIdx.x;
  int t = threadIdx.x;

  if (bid >= 1024) {
    int i = (bid - 1024) * 256 + t;
    if (i < NK * 64 * 64) {
      int c = i & 63, o = (i >> 6) & 63, k = i >> 12;
      wbt[i] = (_Float16)wd[(o * 64 + c) * 9 + k];
    } else {
      int j = i - NK * 64 * 64;
      if (j < NK * 32 * 64) {
        int c = j & 63, o = (j >> 6) & 31, k = j >> 11;
        wbo[j] = (o < 18) ? (_Float16)wo[(o * 64 + c) * 9 + k] : (_Float16)0;
      }
    }
    return;
  }

  int b = bid & 7;         // XCD-aligned: image b handled by XCD (bid % 8) = b
  int h = bid >> 3;
  const float* xb = x + ((size_t)b * NCH) * HWD * HWD + (size_t)h * HWD;
  #pragma unroll 4
  for (int i = 0; i < 32; ++i) {
    int c = (t >> 7) + 2 * i;
    int w = t & 127;
    tile[c][w] = xb[(size_t)c * HWD * HWD + w];
  }
  __syncthreads();
  _Float16* xto = xt + (((size_t)b * HWD + h) * HWD) * NCH;
  #pragma unroll 4
  for (int i = 0; i < 32; ++i) {
    int idx = i * 256 + t;
    int c = idx & 63, w = idx >> 6;
    xto[(size_t)w * NCH + c] = (_Float16)tile[c][w];
  }
}

// ---- fused kernel v15 (= v14, the measured floor ~43 us): 4x16 patch;
// x halo + double-buffered weight taps in LDS; one barrier per tap; in-wave
// shfl offset exchange; LDS epilogue. 36864 B -> 4 blocks/CU, zero-tail grid.
#define PH 4
#define PW 16
#define XR 8
#define XC 20
#define NSLOT (XR * XC)     // 160 slots, 64 halves each (128 B)

__global__ __launch_bounds__(256, 4) void fused_deform_kernel(
    const _Float16* __restrict__ xt, const _Float16* __restrict__ wbt,
    const _Float16* __restrict__ wbo, const float* __restrict__ bo,
    float* __restrict__ out)
{
  __shared__ _Float16 xlds[NSLOT * 64];    // 20480 B (reused as f32 epilogue buf)
  __shared__ _Float16 wlds[2 * 64 * 64];   // 16384 B: two 8 KB weight buffers

  int bid = blockIdx.x;
  int cid = (bid & 7) * 256 + (bid >> 3);  // XCD swizzle (bijective, 2048 % 8 == 0)
  int wp = cid & 7;
  int hp = (cid >> 3) & 31;
  int b  = cid >> 8;                       // = bid & 7 -> image b on XCD b
  int h0 = hp * PH, w0 = wp * PW;

  int t = threadIdx.x;
  int lane = t & 63;
  int wv = t >> 6;
  int pl = lane & 15;
  int cg = lane >> 4;
  int p  = wv * 16 + pl;          // pixel index in 4x16 patch
  int hh = p >> 4, ww = p & 15;
  int h = h0 + hh, w = w0 + ww;

  const _Float16* xtb = xt + ((size_t)b * HWD * HWD) * NCH;

  // ---- stage x halo tile (async, source pre-swizzled, dest linear) ----
  #pragma unroll
  for (int i = 0; i < 5; ++i) {
    int idx = i * 256 + t;                 // 160 slots * 8 chunks = 1280
    int px = idx >> 3, c8 = idx & 7;
    int r = px / XC, c = px - r * XC;
    int yr = min(max(h0 - 2 + r, 0), HWD - 1);
    int xc = min(max(w0 - 2 + c, 0), HWD - 1);
    async_copy16(xlds + idx * 8,
                 xtb + (size_t)(yr * HWD + xc) * NCH + swz(px, c8) * 8);
  }

  // ---- weight stagers: one tap into buffer buf (async, swizzled source) ----
  auto stage_wbo_tap = [&](int k, int buf) {       // 32 rows x 8 chunks = 256
    int row = t >> 3, c8 = t & 7;
    async_copy16(wlds + buf * 4096 + t * 8,
                 wbo + ((size_t)k * 32 + row) * 64 + swz(row, c8) * 8);
  };
  auto stage_wbt_tap = [&](int k, int buf) {       // 64 rows x 8 chunks = 512
    #pragma unroll
    for (int i = 0; i < 2; ++i) {
      int idx = i * 256 + t;
      int row = idx >> 3, c8 = idx & 7;
      async_copy16(wlds + buf * 4096 + idx * 8,
                   wbt + ((size_t)k * 64 + row) * 64 + swz(row, c8) * 8);
    }
  };

  stage_wbo_tap(0, 0);
  __syncthreads();    // all staging (x halo + wbo tap0) complete

  // ======== PHASE 1: offset conv ========
  f32x4 acc2[2];
  acc2[0] = (f32x4){0.f, 0.f, 0.f, 0.f};
  acc2[1] = (f32x4){0.f, 0.f, 0.f, 0.f};

  auto tap1 = [&](int k, int buf) {
    int ky = k / 3, kx = k - ky * 3;
    int y = h + ky - 1, x = w + kx - 1;
    bool ok = (y >= 0) & (y < HWD) & (x >= 0) & (x < HWD);
    int slot = (hh + ky + 1) * XC + (ww + kx + 1);
    const _Float16* sp = xlds + slot * 64;
    h16x8 b0 = *(const h16x8*)(sp + swz(slot, cg) * 8);
    h16x8 b1 = *(const h16x8*)(sp + swz(slot, cg + 4) * 8);
    if (!ok) {
      #pragma unroll
      for (int j = 0; j < 8; ++j) { b0[j] = (_Float16)0; b1[j] = (_Float16)0; }
    }
    const _Float16* wb = wlds + buf * 4096;
    #pragma unroll
    for (int nt = 0; nt < 2; ++nt) {
      int row = nt * 16 + pl;
      h16x8 a0 = *(const h16x8*)(wb + row * 64 + swz(row, cg) * 8);
      h16x8 a1 = *(const h16x8*)(wb + row * 64 + swz(row, cg + 4) * 8);
      acc2[nt] = __builtin_amdgcn_mfma_f32_16x16x32_f16(a0, b0, acc2[nt], 0, 0, 0);
      acc2[nt] = __builtin_amdgcn_mfma_f32_16x16x32_f16(a1, b1, acc2[nt], 0, 0, 0);
    }
  };

  #pragma unroll
  for (int k = 0; k < NK; ++k) {
    if (k < NK - 1) stage_wbo_tap(k + 1, (k + 1) & 1);
    tap1(k, k & 1);
    __syncthreads();
  }

  // prefetch wbt tap0 into buf0 (last read of buf0 was tap1(8), barrier passed)
  stage_wbt_tap(0, 0);

  // ---- offset exchange IN-WAVE via shfl (no LDS buffer, no extra barrier) ----
  h16x2 oo[NK];
  int base = lane & 15;
  #pragma unroll
  for (int k = 0; k < NK; ++k) {
    const int ocy = 2 * k,     nty = ocy >> 4, cgy = (ocy >> 2) & 3, ry = ocy & 3;
    const int ocx = 2 * k + 1, ntx = ocx >> 4, cgx = (ocx >> 2) & 3, rx = ocx & 3;
    float vy = __shfl(acc2[nty][ry], base + cgy * 16, 64) + bo[ocy];
    float vx = __shfl(acc2[ntx][rx], base + cgx * 16, 64) + bo[ocx];
    oo[k][0] = (_Float16)vy;
    oo[k][1] = (_Float16)vx;
  }
  __syncthreads();    // wbt tap0 staged (vmcnt drained)

  // ======== PHASE 2: deformable conv ========
  f32x4 acc[4];
  #pragma unroll
  for (int nt = 0; nt < 4; ++nt) acc[nt] = (f32x4){0.f, 0.f, 0.f, 0.f};

  auto tap2 = [&](int k, int buf) {
    int ky = k / 3, kx = k - ky * 3;
    float py = (float)oo[k][0] + (float)(h - 1 + ky);
    float pxf = (float)oo[k][1] + (float)(w - 1 + kx);
    float y0f = floorf(py), x0f = floorf(pxf);
    float wy1 = py - y0f, wx1 = pxf - x0f;
    float wy0 = 1.f - wy1, wx0 = 1.f - wx1;
    int y0 = (int)y0f, x0 = (int)x0f;
    int sy = y0 - (h0 - 2);
    int sx = x0 - (w0 - 2);

    h16x8 s0, s1;
    #pragma unroll
    for (int j = 0; j < 8; ++j) { s0[j] = (_Float16)0; s1[j] = (_Float16)0; }

    #pragma unroll
    for (int r = 0; r < 4; ++r) {
      int dy = r >> 1, dx = r & 1;
      int yy = y0 + dy, xx = x0 + dx;
      int sr = sy + dy, sc = sx + dx;
      bool okimg = (yy >= 0) & (yy < HWD) & (xx >= 0) & (xx < HWD);
      float wtf = (dy ? wy1 : wy0) * (dx ? wx1 : wx0);
      wtf = okimg ? wtf : 0.f;
      _Float16 wzh = (_Float16)wtf;

      h16x8 g0, g1;
      bool intile = (sr >= 0) & (sr < XR) & (sc >= 0) & (sc < XC);
      if (intile) {
        int slot = sr * XC + sc;
        const _Float16* sp = xlds + slot * 64;
        g0 = *(const h16x8*)(sp + swz(slot, cg) * 8);
        g1 = *(const h16x8*)(sp + swz(slot, cg + 4) * 8);
      } else {
        // rare fallback (|offset| > ~1) or OOB-with-wt0; clamped safe read
        int yc = min(max(yy, 0), HWD - 1);
        int xc2 = min(max(xx, 0), HWD - 1);
        const _Float16* sp = xtb + (size_t)(yc * HWD + xc2) * NCH + cg * 8;
        g0 = *(const h16x8*)(sp);
        g1 = *(const h16x8*)(sp + 32);
      }
      h16x8 wzv;
      #pragma unroll
      for (int j = 0; j < 8; ++j) wzv[j] = wzh;
      s0 = g0 * wzv + s0;     // v_pk_fma_f16
      s1 = g1 * wzv + s1;
    }

    const _Float16* wb = wlds + buf * 4096;
    #pragma unroll
    for (int nt = 0; nt < 4; ++nt) {
      int row = nt * 16 + pl;
      h16x8 a0 = *(const h16x8*)(wb + row * 64 + swz(row, cg) * 8);
      h16x8 a1 = *(const h16x8*)(wb + row * 64 + swz(row, cg + 4) * 8);
      acc[nt] = __builtin_amdgcn_mfma_f32_16x16x32_f16(a0, s0, acc[nt], 0, 0, 0);
      acc[nt] = __builtin_amdgcn_mfma_f32_16x16x32_f16(a1, s1, acc[nt], 0, 0, 0);
    }
  };

  #pragma unroll
  for (int k = 0; k < NK; ++k) {
    if (k < NK - 1) stage_wbt_tap(k + 1, (k + 1) & 1);
    tap2(k, k & 1);
    __syncthreads();
  }

  // ---- epilogue: D col=pixel p, row=oc. Stage via LDS (reuse xlds). ----
  float* ost = (float*)xlds;   // [64 oc][65] = 16640 B
  #pragma unroll
  for (int nt = 0; nt < 4; ++nt) {
    int oc = nt * 16 + cg * 4;
    #pragma unroll
    for (int r = 0; r < 4; ++r)
      ost[(oc + r) * 65 + p] = acc[nt][r];
  }
  __syncthreads();
  #pragma unroll
  for (int i = 0; i < 16; ++i) {
    int idx = i * 256 + t;
    int pp = idx & 63, oc = idx >> 6;
    int hh2 = pp >> 4, ww2 = pp & 15;
    out[(((size_t)b * NCH + oc) * HWD + h0 + hh2) * HWD + w0 + ww2] = ost[oc * 65 + pp];
  }
}

extern "C" void kernel_launch(void* const* d_in, const int* in_sizes, int n_in,
                              void* d_out, int out_size, void* d_ws, size_t ws_size,
                              hipStream_t stream) {
  const float* x     = (const float*)d_in[0];
  const float* w_off = (const float*)d_in[1];
  const float* b_off = (const float*)d_in[2];
  const float* w_def = (const float*)d_in[3];
  float* out = (float*)d_out;

  char* ws = (char*)d_ws;
  _Float16* xt  = (_Float16*)ws;                       // 8*128*128*64*2 = 16,777,216 B
  _Float16* wbt = (_Float16*)(ws + 16777216);          // 9*64*64*2      =     73,728 B
  _Float16* wbo = (_Float16*)(ws + 16777216 + 73728);  // 9*32*64*2      =     36,864 B

  hipLaunchKernelGGL(prep_transpose_kernel, dim3(1240), dim3(256), 0, stream,
                     x, w_def, w_off, xt, wbt, wbo);
  hipLaunchKernelGGL(fused_deform_kernel,   dim3(2048), dim3(256), 0, stream,
                     xt, wbt, wbo, b_off, out);
}

// Round 16
// 49.455 us; speedup vs baseline: 2.3641x; 1.0464x over previous
//
#include <hip/hip_runtime.h>
#include <hip/hip_bf16.h>

#define HWD 128
#define NCH 64
#define NK  9

typedef __attribute__((ext_vector_type(8))) _Float16 h16x8;
typedef __attribute__((ext_vector_type(2))) _Float16 h16x2;
typedef __attribute__((ext_vector_type(4))) float f32x4;

// async 16B global->LDS copy (dest = wave-uniform base + lane*16, linear)
__device__ __forceinline__ void async_copy16(void* lds, const void* g) {
  __builtin_amdgcn_global_load_lds(
      (const __attribute__((address_space(1))) unsigned int*)g,
      (__attribute__((address_space(3))) unsigned int*)lds, 16, 0, 0);
}

__device__ __forceinline__ int swz(int unit, int c) { return (c ^ unit) & 7; }

// ---- merged prep + transpose kernel (vectorized I/O).
// Blocks 0..1023: x NCHW f32 -> xt NHWC fp16, XCD-ALIGNED (b = bid&7).
// Blocks 1024..1239: weight prep (wbt [9k][64o][64c], wbo [9k][32o][64c] fp16).
__global__ __launch_bounds__(256) void prep_transpose_kernel(
    const float* __restrict__ x, const float* __restrict__ wd,
    const float* __restrict__ wo, _Float16* __restrict__ xt,
    _Float16* __restrict__ wbt, _Float16* __restrict__ wbo) {
  __shared__ float tile[64][129];
  int bid = blockIdx.x;
  int t = threadIdx.x;

  if (bid >= 1024) {
    int i = (bid - 1024) * 256 + t;
    if (i < NK * 64 * 64) {
      int c = i & 63, o = (i >> 6) & 63, k = i >> 12;
      wbt[i] = (_Float16)wd[(o * 64 + c) * 9 + k];
    } else {
      int j = i - NK * 64 * 64;
      if (j < NK * 32 * 64) {
        int c = j & 63, o = (j >> 6) & 31, k = j >> 11;
        wbo[j] = (o < 18) ? (_Float16)wo[(o * 64 + c) * 9 + k] : (_Float16)0;
      }
    }
    return;
  }

  int b = bid & 7;         // XCD-aligned: image b handled by XCD (bid % 8) = b
  int h = bid >> 3;
  const float* xb = x + ((size_t)b * NCH) * HWD * HWD + (size_t)h * HWD;
  // float4 loads: 2048 chunks = 64 c x 32 w4
  #pragma unroll
  for (int i = 0; i < 8; ++i) {
    int idx = i * 256 + t;
    int c = idx >> 5, w4 = idx & 31;
    f32x4 v = *(const f32x4*)(xb + (size_t)c * HWD * HWD + w4 * 4);
    tile[c][w4 * 4 + 0] = v[0];
    tile[c][w4 * 4 + 1] = v[1];
    tile[c][w4 * 4 + 2] = v[2];
    tile[c][w4 * 4 + 3] = v[3];
  }
  __syncthreads();
  // h16x8 stores: 1024 chunks = 128 w x 8 c8 (consecutive idx -> contiguous 16B)
  _Float16* xto = xt + (((size_t)b * HWD + h) * HWD) * NCH;
  #pragma unroll
  for (int i = 0; i < 4; ++i) {
    int idx = i * 256 + t;
    int w = idx >> 3, c8 = idx & 7;
    h16x8 v;
    #pragma unroll
    for (int j = 0; j < 8; ++j) v[j] = (_Float16)tile[c8 * 8 + j][w];
    *(h16x8*)(xto + w * NCH + c8 * 8) = v;
  }
}

// ---- fused kernel v16 (= v14 structure, direct-store epilogue): 4x16 patch;
// x halo + double-buffered weight taps in LDS; one barrier per tap; in-wave
// shfl offset exchange. 36864 B -> 4 blocks/CU, zero-tail grid.
#define PH 4
#define PW 16
#define XR 8
#define XC 20
#define NSLOT (XR * XC)     // 160 slots, 64 halves each (128 B)

__global__ __launch_bounds__(256, 4) void fused_deform_kernel(
    const _Float16* __restrict__ xt, const _Float16* __restrict__ wbt,
    const _Float16* __restrict__ wbo, const float* __restrict__ bo,
    float* __restrict__ out)
{
  __shared__ _Float16 xlds[NSLOT * 64];    // 20480 B
  __shared__ _Float16 wlds[2 * 64 * 64];   // 16384 B: two 8 KB weight buffers

  int bid = blockIdx.x;
  int cid = (bid & 7) * 256 + (bid >> 3);  // XCD swizzle (bijective, 2048 % 8 == 0)
  int wp = cid & 7;
  int hp = (cid >> 3) & 31;
  int b  = cid >> 8;                       // = bid & 7 -> image b on XCD b
  int h0 = hp * PH, w0 = wp * PW;

  int t = threadIdx.x;
  int lane = t & 63;
  int wv = t >> 6;
  int pl = lane & 15;
  int cg = lane >> 4;
  int p  = wv * 16 + pl;          // pixel index in 4x16 patch
  int hh = wv, ww = pl;           // (p>>4, p&15)
  int h = h0 + hh, w = w0 + ww;

  const _Float16* xtb = xt + ((size_t)b * HWD * HWD) * NCH;

  // ---- stage x halo tile (async, source pre-swizzled, dest linear) ----
  #pragma unroll
  for (int i = 0; i < 5; ++i) {
    int idx = i * 256 + t;                 // 160 slots * 8 chunks = 1280
    int px = idx >> 3, c8 = idx & 7;
    int r = px / XC, c = px - r * XC;
    int yr = min(max(h0 - 2 + r, 0), HWD - 1);
    int xc = min(max(w0 - 2 + c, 0), HWD - 1);
    async_copy16(xlds + idx * 8,
                 xtb + (size_t)(yr * HWD + xc) * NCH + swz(px, c8) * 8);
  }

  // ---- weight stagers: one tap into buffer buf (async, swizzled source) ----
  auto stage_wbo_tap = [&](int k, int buf) {       // 32 rows x 8 chunks = 256
    int row = t >> 3, c8 = t & 7;
    async_copy16(wlds + buf * 4096 + t * 8,
                 wbo + ((size_t)k * 32 + row) * 64 + swz(row, c8) * 8);
  };
  auto stage_wbt_tap = [&](int k, int buf) {       // 64 rows x 8 chunks = 512
    #pragma unroll
    for (int i = 0; i < 2; ++i) {
      int idx = i * 256 + t;
      int row = idx >> 3, c8 = idx & 7;
      async_copy16(wlds + buf * 4096 + idx * 8,
                   wbt + ((size_t)k * 64 + row) * 64 + swz(row, c8) * 8);
    }
  };

  stage_wbo_tap(0, 0);
  __syncthreads();    // all staging (x halo + wbo tap0) complete

  // ======== PHASE 1: offset conv ========
  f32x4 acc2[2];
  acc2[0] = (f32x4){0.f, 0.f, 0.f, 0.f};
  acc2[1] = (f32x4){0.f, 0.f, 0.f, 0.f};

  auto tap1 = [&](int k, int buf) {
    int ky = k / 3, kx = k - ky * 3;
    int y = h + ky - 1, x = w + kx - 1;
    bool ok = (y >= 0) & (y < HWD) & (x >= 0) & (x < HWD);
    int slot = (hh + ky + 1) * XC + (ww + kx + 1);
    const _Float16* sp = xlds + slot * 64;
    h16x8 b0 = *(const h16x8*)(sp + swz(slot, cg) * 8);
    h16x8 b1 = *(const h16x8*)(sp + swz(slot, cg + 4) * 8);
    if (!ok) {
      #pragma unroll
      for (int j = 0; j < 8; ++j) { b0[j] = (_Float16)0; b1[j] = (_Float16)0; }
    }
    const _Float16* wb = wlds + buf * 4096;
    #pragma unroll
    for (int nt = 0; nt < 2; ++nt) {
      int row = nt * 16 + pl;
      h16x8 a0 = *(const h16x8*)(wb + row * 64 + swz(row, cg) * 8);
      h16x8 a1 = *(const h16x8*)(wb + row * 64 + swz(row, cg + 4) * 8);
      acc2[nt] = __builtin_amdgcn_mfma_f32_16x16x32_f16(a0, b0, acc2[nt], 0, 0, 0);
      acc2[nt] = __builtin_amdgcn_mfma_f32_16x16x32_f16(a1, b1, acc2[nt], 0, 0, 0);
    }
  };

  #pragma unroll
  for (int k = 0; k < NK; ++k) {
    if (k < NK - 1) stage_wbo_tap(k + 1, (k + 1) & 1);
    tap1(k, k & 1);
    __syncthreads();
  }

  // prefetch wbt tap0 into buf0 (last read of buf0 was tap1(8), barrier passed)
  stage_wbt_tap(0, 0);

  // ---- offset exchange IN-WAVE via shfl (no LDS buffer, no extra barrier) ----
  h16x2 oo[NK];
  int base = lane & 15;
  #pragma unroll
  for (int k = 0; k < NK; ++k) {
    const int ocy = 2 * k,     nty = ocy >> 4, cgy = (ocy >> 2) & 3, ry = ocy & 3;
    const int ocx = 2 * k + 1, ntx = ocx >> 4, cgx = (ocx >> 2) & 3, rx = ocx & 3;
    float vy = __shfl(acc2[nty][ry], base + cgy * 16, 64) + bo[ocy];
    float vx = __shfl(acc2[ntx][rx], base + cgx * 16, 64) + bo[ocx];
    oo[k][0] = (_Float16)vy;
    oo[k][1] = (_Float16)vx;
  }
  __syncthreads();    // wbt tap0 staged (vmcnt drained)

  // ======== PHASE 2: deformable conv ========
  f32x4 acc[4];
  #pragma unroll
  for (int nt = 0; nt < 4; ++nt) acc[nt] = (f32x4){0.f, 0.f, 0.f, 0.f};

  auto tap2 = [&](int k, int buf) {
    int ky = k / 3, kx = k - ky * 3;
    float py = (float)oo[k][0] + (float)(h - 1 + ky);
    float pxf = (float)oo[k][1] + (float)(w - 1 + kx);
    float y0f = floorf(py), x0f = floorf(pxf);
    float wy1 = py - y0f, wx1 = pxf - x0f;
    float wy0 = 1.f - wy1, wx0 = 1.f - wx1;
    int y0 = (int)y0f, x0 = (int)x0f;
    int sy = y0 - (h0 - 2);
    int sx = x0 - (w0 - 2);

    h16x8 s0, s1;
    #pragma unroll
    for (int j = 0; j < 8; ++j) { s0[j] = (_Float16)0; s1[j] = (_Float16)0; }

    #pragma unroll
    for (int r = 0; r < 4; ++r) {
      int dy = r >> 1, dx = r & 1;
      int yy = y0 + dy, xx = x0 + dx;
      int sr = sy + dy, sc = sx + dx;
      bool okimg = (yy >= 0) & (yy < HWD) & (xx >= 0) & (xx < HWD);
      float wtf = (dy ? wy1 : wy0) * (dx ? wx1 : wx0);
      wtf = okimg ? wtf : 0.f;
      _Float16 wzh = (_Float16)wtf;

      h16x8 g0, g1;
      bool intile = (sr >= 0) & (sr < XR) & (sc >= 0) & (sc < XC);
      if (intile) {
        int slot = sr * XC + sc;
        const _Float16* sp = xlds + slot * 64;
        g0 = *(const h16x8*)(sp + swz(slot, cg) * 8);
        g1 = *(const h16x8*)(sp + swz(slot, cg + 4) * 8);
      } else {
        // rare fallback (|offset| > ~1) or OOB-with-wt0; clamped safe read
        int yc = min(max(yy, 0), HWD - 1);
        int xc2 = min(max(xx, 0), HWD - 1);
        const _Float16* sp = xtb + (size_t)(yc * HWD + xc2) * NCH + cg * 8;
        g0 = *(const h16x8*)(sp);
        g1 = *(const h16x8*)(sp + 32);
      }
      h16x8 wzv;
      #pragma unroll
      for (int j = 0; j < 8; ++j) wzv[j] = wzh;
      s0 = g0 * wzv + s0;     // v_pk_fma_f16
      s1 = g1 * wzv + s1;
    }

    const _Float16* wb = wlds + buf * 4096;
    #pragma unroll
    for (int nt = 0; nt < 4; ++nt) {
      int row = nt * 16 + pl;
      h16x8 a0 = *(const h16x8*)(wb + row * 64 + swz(row, cg) * 8);
      h16x8 a1 = *(const h16x8*)(wb + row * 64 + swz(row, cg + 4) * 8);
      acc[nt] = __builtin_amdgcn_mfma_f32_16x16x32_f16(a0, s0, acc[nt], 0, 0, 0);
      acc[nt] = __builtin_amdgcn_mfma_f32_16x16x32_f16(a1, s1, acc[nt], 0, 0, 0);
    }
  };

  #pragma unroll
  for (int k = 0; k < NK; ++k) {
    if (k < NK - 1) stage_wbt_tap(k + 1, (k + 1) & 1);
    tap2(k, k & 1);
    if (k < NK - 1) __syncthreads();
  }

  // ---- epilogue: DIRECT stores (no LDS, no barriers).
  // lane (pl,cg) holds oc = nt*16+cg*4+r for pixel (h0+wv, w0+pl):
  // lanes 0-15 per cg = 64B contiguous segment; 4 segments per instr.
  #pragma unroll
  for (int nt = 0; nt < 4; ++nt) {
    #pragma unroll
    for (int r = 0; r < 4; ++r) {
      int oc = nt * 16 + cg * 4 + r;
      out[(((size_t)b * NCH + oc) * HWD + h) * HWD + w0 + pl] = acc[nt][r];
    }
  }
}

extern "C" void kernel_launch(void* const* d_in, const int* in_sizes, int n_in,
                              void* d_out, int out_size, void* d_ws, size_t ws_size,
                              hipStream_t stream) {
  const float* x     = (const float*)d_in[0];
  const float* w_off = (const float*)d_in[1];
  const float* b_off = (const float*)d_in[2];
  const float* w_def = (const float*)d_in[3];
  float* out = (float*)d_out;

  char* ws = (char*)d_ws;
  _Float16* xt  = (_Float16*)ws;                       // 8*128*128*64*2 = 16,777,216 B
  _Float16* wbt = (_Float16*)(ws + 16777216);          // 9*64*64*2      =     73,728 B
  _Float16* wbo = (_Float16*)(ws + 16777216 + 73728);  // 9*32*64*2      =     36,864 B

  hipLaunchKernelGGL(prep_transpose_kernel, dim3(1240), dim3(256), 0, stream,
                     x, w_def, w_off, xt, wbt, wbo);
  hipLaunchKernelGGL(fused_deform_kernel,   dim3(2048), dim3(256), 0, stream,
                     xt, wbt, wbo, b_off, out);
}

// Round 19
// 48.307 us; speedup vs baseline: 2.4203x; 1.0238x over previous
//
#include <hip/hip_runtime.h>
#include <hip/hip_bf16.h>

#define HWD 128
#define NCH 64
#define NK  9

typedef __attribute__((ext_vector_type(8))) _Float16 h16x8;
typedef __attribute__((ext_vector_type(2))) _Float16 h16x2;
typedef __attribute__((ext_vector_type(4))) float f32x4;

// async 16B global->LDS copy (dest = wave-uniform base + lane*16, linear)
__device__ __forceinline__ void async_copy16(void* lds, const void* g) {
  __builtin_amdgcn_global_load_lds(
      (const __attribute__((address_space(1))) unsigned int*)g,
      (__attribute__((address_space(3))) unsigned int*)lds, 16, 0, 0);
}

__device__ __forceinline__ int swz(int unit, int c) { return (c ^ unit) & 7; }

// ---- merged prep + transpose kernel (vectorized I/O).
// Blocks 0..1023: x NCHW f32 -> xt NHWC fp16, XCD-ALIGNED (b = bid&7).
// Blocks 1024..1239: weight prep (wbt [9k][64o][64c], wbo [9k][32o][64c] fp16).
__global__ __launch_bounds__(256) void prep_transpose_kernel(
    const float* __restrict__ x, const float* __restrict__ wd,
    const float* __restrict__ wo, _Float16* __restrict__ xt,
    _Float16* __restrict__ wbt, _Float16* __restrict__ wbo) {
  __shared__ float tile[64][129];
  int bid = blockIdx.x;
  int t = threadIdx.x;

  if (bid >= 1024) {
    int i = (bid - 1024) * 256 + t;
    if (i < NK * 64 * 64) {
      int c = i & 63, o = (i >> 6) & 63, k = i >> 12;
      wbt[i] = (_Float16)wd[(o * 64 + c) * 9 + k];
    } else {
      int j = i - NK * 64 * 64;
      if (j < NK * 32 * 64) {
        int c = j & 63, o = (j >> 6) & 31, k = j >> 11;
        wbo[j] = (o < 18) ? (_Float16)wo[(o * 64 + c) * 9 + k] : (_Float16)0;
      }
    }
    return;
  }

  int b = bid & 7;         // XCD-aligned: image b handled by XCD (bid % 8) = b
  int h = bid >> 3;
  const float* xb = x + ((size_t)b * NCH) * HWD * HWD + (size_t)h * HWD;
  #pragma unroll
  for (int i = 0; i < 8; ++i) {
    int idx = i * 256 + t;
    int c = idx >> 5, w4 = idx & 31;
    f32x4 v = *(const f32x4*)(xb + (size_t)c * HWD * HWD + w4 * 4);
    tile[c][w4 * 4 + 0] = v[0];
    tile[c][w4 * 4 + 1] = v[1];
    tile[c][w4 * 4 + 2] = v[2];
    tile[c][w4 * 4 + 3] = v[3];
  }
  __syncthreads();
  _Float16* xto = xt + (((size_t)b * HWD + h) * HWD) * NCH;
  #pragma unroll
  for (int i = 0; i < 4; ++i) {
    int idx = i * 256 + t;
    int w = idx >> 3, c8 = idx & 7;
    h16x8 v;
    #pragma unroll
    for (int j = 0; j < 8; ++j) v[j] = (_Float16)tile[c8 * 8 + j][w];
    *(h16x8*)(xto + w * NCH + c8 * 8) = v;
  }
}

// ---- fused kernel v19 (= v16, the verified 42.3 us structure, + PAIRED wbo
// staging): phase 1 stages TWO wbo taps per 8 KB buffer -> 5 sync points
// instead of 9, each amortizing 2 taps of compute. All sync = __syncthreads
// (full drain; proven). Phase 2 unchanged. 36864 B LDS -> 4 blocks/CU.
#define PH 4
#define PW 16
#define XR 8
#define XC 20
#define NSLOT (XR * XC)     // 160 slots, 64 halves each (128 B)

__global__ __launch_bounds__(256, 4) void fused_deform_kernel(
    const _Float16* __restrict__ xt, const _Float16* __restrict__ wbt,
    const _Float16* __restrict__ wbo, const float* __restrict__ bo,
    float* __restrict__ out)
{
  __shared__ _Float16 xlds[NSLOT * 64];    // 20480 B
  __shared__ _Float16 wlds[2 * 64 * 64];   // 16384 B: two 8 KB weight buffers

  int bid = blockIdx.x;
  int cid = (bid & 7) * 256 + (bid >> 3);  // XCD swizzle (bijective, 2048 % 8 == 0)
  int wp = cid & 7;
  int hp = (cid >> 3) & 31;
  int b  = cid >> 8;                       // = bid & 7 -> image b on XCD b
  int h0 = hp * PH, w0 = wp * PW;

  int t = threadIdx.x;
  int lane = t & 63;
  int wv = t >> 6;
  int pl = lane & 15;
  int cg = lane >> 4;
  int hh = wv, ww = pl;
  int h = h0 + hh, w = w0 + ww;

  const _Float16* xtb = xt + ((size_t)b * HWD * HWD) * NCH;

  // ---- stage x halo tile (async, source pre-swizzled, dest linear) ----
  #pragma unroll
  for (int i = 0; i < 5; ++i) {
    int idx = i * 256 + t;                 // 160 slots * 8 chunks = 1280
    int px = idx >> 3, c8 = idx & 7;
    int r = px / XC, c = px - r * XC;
    int yr = min(max(h0 - 2 + r, 0), HWD - 1);
    int xc = min(max(w0 - 2 + c, 0), HWD - 1);
    async_copy16(xlds + idx * 8,
                 xtb + (size_t)(yr * HWD + xc) * NCH + swz(px, c8) * 8);
  }

  // ---- weight stagers (async, swizzled source, linear dest) ----
  // wbo pair j (taps 2j, 2j+1): 64 rows x 8 chunks = 2 instr/thread (8 KB)
  auto stage_wbo_pair = [&](int j, int buf) {
    #pragma unroll
    for (int i = 0; i < 2; ++i) {
      int idx = i * 256 + t;
      int row = idx >> 3, c8 = idx & 7;
      async_copy16(wlds + buf * 4096 + idx * 8,
                   wbo + ((size_t)j * 64 + row) * 64 + swz(row, c8) * 8);
    }
  };
  auto stage_wbo_last = [&](int buf) {     // tap 8 alone: 32 rows (4 KB)
    int row = t >> 3, c8 = t & 7;
    async_copy16(wlds + buf * 4096 + t * 8,
                 wbo + ((size_t)8 * 32 + row) * 64 + swz(row, c8) * 8);
  };
  auto stage_wbt_tap = [&](int k, int buf) {       // 64 rows (8 KB)
    #pragma unroll
    for (int i = 0; i < 2; ++i) {
      int idx = i * 256 + t;
      int row = idx >> 3, c8 = idx & 7;
      async_copy16(wlds + buf * 4096 + idx * 8,
                   wbt + ((size_t)k * 64 + row) * 64 + swz(row, c8) * 8);
    }
  };

  stage_wbo_pair(0, 0);
  __syncthreads();    // all staging (x halo + wbo taps 0,1) complete

  // ======== PHASE 1: offset conv ========
  f32x4 acc2[2];
  acc2[0] = (f32x4){0.f, 0.f, 0.f, 0.f};
  acc2[1] = (f32x4){0.f, 0.f, 0.f, 0.f};

  // tap k from buffer buf, half hf (rows hf*32 .. hf*32+31)
  auto tap1 = [&](int k, int buf, int hf) {
    int ky = k / 3, kx = k - ky * 3;
    int y = h + ky - 1, x = w + kx - 1;
    bool ok = (y >= 0) & (y < HWD) & (x >= 0) & (x < HWD);
    int slot = (hh + ky + 1) * XC + (ww + kx + 1);
    const _Float16* sp = xlds + slot * 64;
    h16x8 b0 = *(const h16x8*)(sp + swz(slot, cg) * 8);
    h16x8 b1 = *(const h16x8*)(sp + swz(slot, cg + 4) * 8);
    if (!ok) {
      #pragma unroll
      for (int j = 0; j < 8; ++j) { b0[j] = (_Float16)0; b1[j] = (_Float16)0; }
    }
    const _Float16* wb = wlds + buf * 4096;
    #pragma unroll
    for (int nt = 0; nt < 2; ++nt) {
      int row = hf * 32 + nt * 16 + pl;
      h16x8 a0 = *(const h16x8*)(wb + row * 64 + swz(row, cg) * 8);
      h16x8 a1 = *(const h16x8*)(wb + row * 64 + swz(row, cg + 4) * 8);
      acc2[nt] = __builtin_amdgcn_mfma_f32_16x16x32_f16(a0, b0, acc2[nt], 0, 0, 0);
      acc2[nt] = __builtin_amdgcn_mfma_f32_16x16x32_f16(a1, b1, acc2[nt], 0, 0, 0);
    }
  };

  // 5 sync points: pairs (0,1)(2,3)(4,5)(6,7)(8)
  #pragma unroll
  for (int j = 0; j < 5; ++j) {
    if (j < 3)       stage_wbo_pair(j + 1, (j + 1) & 1);
    else if (j == 3) stage_wbo_last((j + 1) & 1);        // tap 8 -> buf0
    else             stage_wbt_tap(0, 1);                // wbt0 -> buf1
    tap1(2 * j, j & 1, 0);
    if (j < 4) tap1(2 * j + 1, j & 1, 1);
    __syncthreads();
  }

  // ---- offset exchange IN-WAVE via shfl (no LDS buffer, no extra barrier) ----
  h16x2 oo[NK];
  int base = lane & 15;
  #pragma unroll
  for (int k = 0; k < NK; ++k) {
    const int ocy = 2 * k,     nty = ocy >> 4, cgy = (ocy >> 2) & 3, ry = ocy & 3;
    const int ocx = 2 * k + 1, ntx = ocx >> 4, cgx = (ocx >> 2) & 3, rx = ocx & 3;
    float vy = __shfl(acc2[nty][ry], base + cgy * 16, 64) + bo[ocy];
    float vx = __shfl(acc2[ntx][rx], base + cgx * 16, 64) + bo[ocx];
    oo[k][0] = (_Float16)vy;
    oo[k][1] = (_Float16)vx;
  }

  // ======== PHASE 2: deformable conv (wbt0 in buf1; tap k reads buf (k+1)&1) ====
  f32x4 acc[4];
  #pragma unroll
  for (int nt = 0; nt < 4; ++nt) acc[nt] = (f32x4){0.f, 0.f, 0.f, 0.f};

  auto tap2 = [&](int k, int buf) {
    int ky = k / 3, kx = k - ky * 3;
    float py = (float)oo[k][0] + (float)(h - 1 + ky);
    float pxf = (float)oo[k][1] + (float)(w - 1 + kx);
    float y0f = floorf(py), x0f = floorf(pxf);
    float wy1 = py - y0f, wx1 = pxf - x0f;
    float wy0 = 1.f - wy1, wx0 = 1.f - wx1;
    int y0 = (int)y0f, x0 = (int)x0f;
    int sy = y0 - (h0 - 2);
    int sx = x0 - (w0 - 2);

    h16x8 s0, s1;
    #pragma unroll
    for (int j = 0; j < 8; ++j) { s0[j] = (_Float16)0; s1[j] = (_Float16)0; }

    #pragma unroll
    for (int r = 0; r < 4; ++r) {
      int dy = r >> 1, dx = r & 1;
      int yy = y0 + dy, xx = x0 + dx;
      int sr = sy + dy, sc = sx + dx;
      bool okimg = (yy >= 0) & (yy < HWD) & (xx >= 0) & (xx < HWD);
      float wtf = (dy ? wy1 : wy0) * (dx ? wx1 : wx0);
      wtf = okimg ? wtf : 0.f;
      _Float16 wzh = (_Float16)wtf;

      h16x8 g0, g1;
      bool intile = (sr >= 0) & (sr < XR) & (sc >= 0) & (sc < XC);
      if (intile) {
        int slot = sr * XC + sc;
        const _Float16* sp = xlds + slot * 64;
        g0 = *(const h16x8*)(sp + swz(slot, cg) * 8);
        g1 = *(const h16x8*)(sp + swz(slot, cg + 4) * 8);
      } else {
        // rare fallback (|offset| > ~1) or OOB-with-wt0; clamped safe read
        int yc = min(max(yy, 0), HWD - 1);
        int xc2 = min(max(xx, 0), HWD - 1);
        const _Float16* sp = xtb + (size_t)(yc * HWD + xc2) * NCH + cg * 8;
        g0 = *(const h16x8*)(sp);
        g1 = *(const h16x8*)(sp + 32);
      }
      h16x8 wzv;
      #pragma unroll
      for (int j = 0; j < 8; ++j) wzv[j] = wzh;
      s0 = g0 * wzv + s0;     // v_pk_fma_f16
      s1 = g1 * wzv + s1;
    }

    const _Float16* wb = wlds + buf * 4096;
    #pragma unroll
    for (int nt = 0; nt < 4; ++nt) {
      int row = nt * 16 + pl;
      h16x8 a0 = *(const h16x8*)(wb + row * 64 + swz(row, cg) * 8);
      h16x8 a1 = *(const h16x8*)(wb + row * 64 + swz(row, cg + 4) * 8);
      acc[nt] = __builtin_amdgcn_mfma_f32_16x16x32_f16(a0, s0, acc[nt], 0, 0, 0);
      acc[nt] = __builtin_amdgcn_mfma_f32_16x16x32_f16(a1, s1, acc[nt], 0, 0, 0);
    }
  };

  // iter k: stage wbt(k+1) -> buf k&1 (its last reader tap2(k-1) finished
  // before the previous __syncthreads); compute tap k from buf (k+1)&1.
  #pragma unroll
  for (int k = 0; k < NK; ++k) {
    if (k < NK - 1) stage_wbt_tap(k + 1, k & 1);
    tap2(k, (k + 1) & 1);
    if (k < NK - 1) __syncthreads();
  }

  // ---- epilogue: DIRECT stores (no LDS, no barriers) ----
  #pragma unroll
  for (int nt = 0; nt < 4; ++nt) {
    #pragma unroll
    for (int r = 0; r < 4; ++r) {
      int oc = nt * 16 + cg * 4 + r;
      out[(((size_t)b * NCH + oc) * HWD + h) * HWD + w0 + pl] = acc[nt][r];
    }
  }
}

extern "C" void kernel_launch(void* const* d_in, const int* in_sizes, int n_in,
                              void* d_out, int out_size, void* d_ws, size_t ws_size,
                              hipStream_t stream) {
  const float* x     = (const float*)d_in[0];
  const float* w_off = (const float*)d_in[1];
  const float* b_off = (const float*)d_in[2];
  const float* w_def = (const float*)d_in[3];
  float* out = (float*)d_out;

  char* ws = (char*)d_ws;
  _Float16* xt  = (_Float16*)ws;                       // 8*128*128*64*2 = 16,777,216 B
  _Float16* wbt = (_Float16*)(ws + 16777216);          // 9*64*64*2      =     73,728 B
  _Float16* wbo = (_Float16*)(ws + 16777216 + 73728);  // 9*32*64*2      =     36,864 B

  hipLaunchKernelGGL(prep_transpose_kernel, dim3(1240), dim3(256), 0, stream,
                     x, w_def, w_off, xt, wbt, wbo);
  hipLaunchKernelGGL(fused_deform_kernel,   dim3(2048), dim3(256), 0, stream,
                     xt, wbt, wbo, b_off, out);
}